// Round 12
// baseline (490.666 us; speedup 1.0000x reference)
//
#include <hip/hip_runtime.h>
#include <hip/hip_bf16.h>

// LocalizedFiltering: two shifted 2-tap causal convs + residual + RMSNorm.
// Fused-K form: A'[u] = U[u] ‖ U[u+1] (U = Xbf for GEMM1, A2 for GEMM2):
//   A2[u+1] = Xbf'[u] @ [W1lo;W1hi] + b1        (K=2048, N=512)
//   Zo[u]   = A2'[u]  @ [W2lo;W2hi]             (K=1024, N=1024), then +b2+res+RMS.
// GEMM: round-8 structure verbatim (256x256, BK=64, paired K-tiles sharing one
// 257-row A slice, vmcnt(4) mid-pair / vmcnt(0) pair-end) but with
// v_mfma_f32_32x32x16_bf16 fragments (m06: 2382 vs 2075 TF; half the instructions).

#define EDIM 1024
#define HDIM 512
#define LSEQ 8192
#define BSEQ 8
#define SEQR 8193                 // L+1
#define MTOT (BSEQ * SEQR)        // 65544 extended rows
#define XROWS 66048               // slack rows (zeroed)

using v8s = __attribute__((ext_vector_type(8))) short;
using v16f = __attribute__((ext_vector_type(16))) float;

__device__ __forceinline__ unsigned short f2b(float f) {
  union { float f; unsigned u; } v; v.f = f;
  unsigned r = v.u + 0x7fffu + ((v.u >> 16) & 1u);   // RNE
  return (unsigned short)(r >> 16);
}
__device__ __forceinline__ float b2f(unsigned short h) {
  union { unsigned u; float f; } v; v.u = ((unsigned)h) << 16; return v.f;
}
__device__ __forceinline__ void gl_lds16(const void* g, void* l) {
  __builtin_amdgcn_global_load_lds((const __attribute__((address_space(1))) void*)g,
                                   (__attribute__((address_space(3))) void*)l, 16, 0, 0);
}

// -------- merged prep: W1c/W2c transposed-cat bf16 weights + c2b gather --------
__device__ __forceinline__ void trns64(const float* __restrict__ src, int src_ld, int src_c0,
                                       unsigned short* __restrict__ dst, int dst_ld, int dst_k0,
                                       int n0, int k0, float (*t)[65], int tx, int ty) {
#pragma unroll
  for (int yy = 0; yy < 64; yy += 4)
    t[yy + ty][tx] = src[(size_t)(k0 + yy + ty) * src_ld + src_c0 + n0 + tx];
  __syncthreads();
#pragma unroll
  for (int yy = 0; yy < 64; yy += 4)
    dst[(size_t)(n0 + yy + ty) * dst_ld + dst_k0 + k0 + tx] = f2b(t[tx][yy + ty]);
}

__global__ __launch_bounds__(256) void prep_all(const float* __restrict__ W1,
                                                const float* __restrict__ W2,
                                                const float* __restrict__ lf2,
                                                const int* __restrict__ preidx,
                                                unsigned short* __restrict__ W1c,
                                                unsigned short* __restrict__ W2c,
                                                unsigned short* __restrict__ c2b) {
  __shared__ float t[64][65];
  const int bk = blockIdx.x;
  const int tid = threadIdx.x;
  if (bk == 512) {
    for (int c = tid; c < HDIM; c += 256)
#pragma unroll
      for (int b = 0; b < BSEQ; ++b)
        c2b[b * HDIM + c] = f2b(lf2[(size_t)preidx[b] * HDIM + c]);
    return;
  }
  const int tx = tid & 63, ty = tid >> 6;
  const int which = bk >> 7, s = bk & 127;
  if (which == 0)       trns64(W1, 1024, 0,    W1c, 2048, 0,    (s & 7) * 64,  (s >> 3) * 64, t, tx, ty);
  else if (which == 1)  trns64(W1, 1024, 512,  W1c, 2048, 1024, (s & 7) * 64,  (s >> 3) * 64, t, tx, ty);
  else if (which == 2)  trns64(W2, 2048, 0,    W2c, 1024, 0,    (s & 15) * 64, (s >> 4) * 64, t, tx, ty);
  else                  trns64(W2, 2048, 1024, W2c, 1024, 512,  (s & 15) * 64, (s >> 4) * 64, t, tx, ty);
}

// -------- cvt: bf16 extended-A (cache row + shifted tokens, zero pad to XROWS) --------
__global__ __launch_bounds__(256) void cvt_full(const float* __restrict__ inputs,
                                                const float* __restrict__ lf1,
                                                const int* __restrict__ preidx,
                                                unsigned short* __restrict__ Xbf) {
  const int r = blockIdx.x * 4 + (threadIdx.x >> 6);   // 0..XROWS-1
  const int lane = threadIdx.x & 63;
  unsigned short* dst = Xbf + (size_t)r * EDIM;
  if (r >= MTOT) {
#pragma unroll
    for (int c = lane * 4; c < EDIM; c += 256)
      *(ushort4*)&dst[c] = (ushort4){0, 0, 0, 0};
    return;
  }
  const int b = r / SEQR, rr = r % SEQR;
  const float* src = (rr == 0) ? (lf1 + (size_t)preidx[b] * EDIM)
                               : (inputs + (size_t)(b * LSEQ + rr - 1) * EDIM);
#pragma unroll
  for (int c = lane * 4; c < EDIM; c += 256) {
    const float4 v = *(const float4*)(src + c);
    *(ushort4*)&dst[c] = (ushort4){f2b(v.x), f2b(v.y), f2b(v.z), f2b(v.w)};
  }
}

// -------- fixup: cache rows of A2 (blk 7) + tail rows 65537..65543 (blk 0..6) --------
__global__ __launch_bounds__(512) void fixup_full(const unsigned short* __restrict__ Xbf,
                                                  const unsigned short* __restrict__ W1c,
                                                  const float* __restrict__ b1,
                                                  const unsigned short* __restrict__ c2b,
                                                  unsigned short* __restrict__ A2) {
  const int blk = blockIdx.x;        // 0..7
  const int tid = threadIdx.x;       // 512
  if (blk == 7) {
#pragma unroll
    for (int b = 0; b < BSEQ; ++b)
      A2[(size_t)(b * SEQR) * HDIM + tid] = c2b[b * HDIM + tid];
    return;
  }
  const int r = 65536 + blk;                         // ext rows 65536..65542
  const unsigned short* a = Xbf + (size_t)r * EDIM;  // 2048 contiguous bf16
  const unsigned short* wrow = W1c + (size_t)tid * 2048;
  float s = 0.f;
  for (int k = 0; k < 2048; k += 8) {
    const v8s av = *(const v8s*)&a[k];
    const v8s wv = *(const v8s*)&wrow[k];
#pragma unroll
    for (int j = 0; j < 8; ++j)
      s += b2f((unsigned short)av[j]) * b2f((unsigned short)wv[j]);
  }
  A2[(size_t)(r + 1) * HDIM + tid] = f2b(s + b1[tid]);
}

// ======= paired-K 256x256 GEMM, BK=64, 8 waves (2m x 4n), 32x32x16 MFMA =======
// LDS: A pair-bufs [257r x 64c] @0/@16512 (elems); B bufs @33024 (B_A), @49408 (B_B).
// Wave tile 128x64: 4 m-frags x 2 n-frags of 32x32. Per lane: A row = l&31,
// k-half = l>>5 (8 contig bf16); C/D: col=l&31, row=(g&3)+8*(g>>2)+4*(l>>5) [m74/m101].
#define PHASE32(p, boA_, off_)                                                         \
  {                                                                                    \
    v8s af[4];                                                                         \
    const int arow = (p) * 64 + wm * 32 + l31 + (off_);                                \
    const int axr = arow & 7;                                                          \
    _Pragma("unroll") for (int kk = 0; kk < 4; ++kk)                                   \
      af[kk] = *(const v8s*)&lds[(boA_) + arow * 64 + (((kk * 2 + lhi) ^ axr) << 3)];  \
    __builtin_amdgcn_s_setprio(1);                                                     \
    _Pragma("unroll") for (int nc = 0; nc < 2; ++nc)                                   \
    _Pragma("unroll") for (int kk = 0; kk < 4; ++kk)                                   \
      acc[p][nc] = __builtin_amdgcn_mfma_f32_32x32x16_bf16(                            \
          af[kk], bfr[nc][kk], acc[p][nc], 0, 0, 0);                                   \
    __builtin_amdgcn_s_setprio(0);                                                     \
  }

#define LOAD_BFR32(boB_)                                                               \
  _Pragma("unroll") for (int nc = 0; nc < 2; ++nc) {                                   \
    const int brow = wn * 64 + nc * 32 + l31;                                          \
    const int bxr = brow & 7;                                                          \
    _Pragma("unroll") for (int kk = 0; kk < 4; ++kk)                                   \
      bfr[nc][kk] = *(const v8s*)&lds[(boB_) + brow * 64 +                             \
                                      (((kk * 2 + lhi) ^ bxr) << 3)];                  \
  }

#define STEP32(boA_, off_)                                                             \
  PHASE32(0, boA_, off_) PHASE32(1, boA_, off_)                                        \
  PHASE32(2, boA_, off_) PHASE32(3, boA_, off_)

template <int K, int NT, bool SHIFTC, bool AMAP>
__global__ __launch_bounds__(512, 2) void gemm_pair(const unsigned short* __restrict__ A,
                                                    const unsigned short* __restrict__ B,
                                                    unsigned short* __restrict__ C,
                                                    const float* __restrict__ bias,
                                                    int q, int r) {
  constexpr int NH = K / 128;          // pairs
  constexpr int LDA = K / 2;           // underlying row stride
  constexpr int N = NT * 256;
  constexpr int A0 = 0, A1 = 16512, B_A = 33024, B_B = 49408;   // elem offsets
  __shared__ __align__(16) unsigned short lds[65792];           // 131584 B

  const int h = blockIdx.x;
  const int xcd = h & 7, idx = h >> 3;
  const int tsw = (xcd < r ? xcd * (q + 1) : r * (q + 1) + (xcd - r) * q) + idx;
  const int mt = tsw / NT, nt = tsw % NT;   // n-fast: neighbors share A m-panel
  const size_t m0 = (size_t)mt * 256, n0 = (size_t)nt * 256;
  const int tid = threadIdx.x;
  const int w = tid >> 6, lane = tid & 63;
  const int wm = w >> 2, wn = w & 3;
  const int l31 = lane & 31, lhi = lane >> 5;
  const int srow = tid >> 3, slot = tid & 7;
  const int gslot = slot ^ (srow & 7);            // pre-swizzled global 16B-slot
  const int dAB = srow * 64 + slot * 8;           // linear LDS dest = wavebase + lane*16B
  const int aBase = (int)m0 + (AMAP ? ((int)m0 >> 13) : 0);  // underlying base row

  // stage underlying A slice for pair i: rows aBase..aBase+256, cols [i*64, i*64+64)
  auto stageApair = [&](int dstE, int i) {
#pragma unroll
    for (int j = 0; j < 4; ++j) {
      const int rr = j * 64 + (tid >> 3);
      gl_lds16(A + (size_t)(aBase + rr) * LDA + i * 64 + ((tid & 7) ^ (rr & 7)) * 8,
               &lds[dstE + rr * 64 + (tid & 7) * 8]);
    }
    if (tid < 8)   // tail row 256 (256&7==0 -> unswizzled is consistent)
      gl_lds16(A + (size_t)(aBase + 256) * LDA + i * 64 + tid * 8,
               &lds[dstE + 256 * 64 + tid * 8]);
  };
  // stage B K-tile t (256 n-rows x 64 cols), hh = row-half
  auto stageB = [&](int dstE, int hh, int t) {
    const unsigned short* s = B + (size_t)(n0 + hh * 128 + srow) * K + t * 64 + gslot * 8;
    unsigned short* d = &lds[dstE + hh * 8192 + dAB];
    gl_lds16(s, d);
    gl_lds16(s + (size_t)64 * K, d + 4096);
  };

  v16f acc[4][2];
#pragma unroll
  for (int i = 0; i < 4; ++i)
#pragma unroll
    for (int j = 0; j < 2; ++j)
#pragma unroll
      for (int g = 0; g < 16; ++g) acc[i][j][g] = 0.f;

  // prologue: A(pair 0) + B_A(tile 0); full drain
  stageApair(A0, 0);
  stageB(B_A, 0, 0); stageB(B_A, 1, 0);
  asm volatile("s_waitcnt vmcnt(0)" ::: "memory");
  __builtin_amdgcn_s_barrier();

#pragma unroll 1
  for (int i = 0; i < NH - 1; ++i) {
    const int boA = (i & 1) ? A1 : A0;
    const int soA = (i & 1) ? A0 : A1;
    v8s bfr[2][4];
    // ---- step alpha (K-tile i): issue B(beta)[4] then A(pair i+1)[4+tail] ----
    stageB(B_B, 0, i + NH); stageB(B_B, 1, i + NH);
    stageApair(soA, i + 1);
    LOAD_BFR32(B_A)
    STEP32(boA, 0)
    // mid-pair: retire the 4 B(beta) (oldest); A(pair i+1) stays in flight
    asm volatile("s_waitcnt vmcnt(4)" ::: "memory");
    __builtin_amdgcn_s_barrier();
    // ---- step beta (K-tile i+NH): issue B(alpha, i+1)[4] ----
    stageB(B_A, 0, i + 1); stageB(B_A, 1, i + 1);
    LOAD_BFR32(B_B)
    STEP32(boA, 1)
    // pair end: drain everything (A pair i+1 had a full pair of flight time)
    asm volatile("s_waitcnt vmcnt(0)" ::: "memory");
    __builtin_amdgcn_s_barrier();
  }
  { // last pair (i = NH-1): only B(beta) staged; mid wait MUST be vmcnt(0)
    const int boA = ((NH - 1) & 1) ? A1 : A0;
    v8s bfr[2][4];
    stageB(B_B, 0, 2 * NH - 1); stageB(B_B, 1, 2 * NH - 1);
    LOAD_BFR32(B_A)
    STEP32(boA, 0)
    asm volatile("s_waitcnt vmcnt(0)" ::: "memory");
    __builtin_amdgcn_s_barrier();
    LOAD_BFR32(B_B)
    STEP32(boA, 1)
  }

#pragma unroll
  for (int mr = 0; mr < 4; ++mr)
#pragma unroll
    for (int nc = 0; nc < 2; ++nc) {
      const size_t col = n0 + wn * 64 + nc * 32 + l31;
      float bv = 0.f;
      if constexpr (SHIFTC) bv = bias[col];
#pragma unroll
      for (int g = 0; g < 16; ++g) {
        const size_t row = m0 + mr * 64 + wm * 32 + 4 * lhi + (g & 3) + 8 * (g >> 2) +
                           (SHIFTC ? 1 : 0);
        C[row * N + col] = f2b(acc[mr][nc][g] + bv);
      }
    }
}

// ---------- epilogue: + b2 + residual(bf16 Xbf) + RMSNorm, one block per token ----------
__global__ __launch_bounds__(256) void epilogue_full(
    const unsigned short* __restrict__ Zo, const unsigned short* __restrict__ Xbf,
    const float* __restrict__ b2, const float* __restrict__ lnw,
    float* __restrict__ out) {
  const int u = blockIdx.x;                       // token id 0..65535
  const size_t rx = (size_t)u + (u >> 13) + 1;    // token's ext row in Xbf
  const int tid = threadIdx.x;
  const int j0 = tid * 4;

  const ushort4 z = *(const ushort4*)&Zo[(size_t)u * EDIM + j0];
  const ushort4 xb = *(const ushort4*)&Xbf[rx * EDIM + j0];   // = bf16(inputs[token])
  const float4 bb = *(const float4*)&b2[j0];
  const float4 lw = *(const float4*)&lnw[j0];

  const float x0 = b2f(z.x) + bb.x + b2f(xb.x);
  const float x1 = b2f(z.y) + bb.y + b2f(xb.y);
  const float x2 = b2f(z.z) + bb.z + b2f(xb.z);
  const float x3 = b2f(z.w) + bb.w + b2f(xb.w);

  float ss = x0 * x0 + x1 * x1 + x2 * x2 + x3 * x3;
#pragma unroll
  for (int o = 32; o > 0; o >>= 1) ss += __shfl_xor(ss, o, 64);
  __shared__ float sp[4];
  if ((tid & 63) == 0) sp[tid >> 6] = ss;
  __syncthreads();
  const float tot = sp[0] + sp[1] + sp[2] + sp[3];
  const float scale = rsqrtf(tot * (1.0f / EDIM) + 1e-6f);

  float4 o4;
  o4.x = x0 * scale * lw.x; o4.y = x1 * scale * lw.y;
  o4.z = x2 * scale * lw.z; o4.w = x3 * scale * lw.w;
  *(float4*)&out[(size_t)u * EDIM + j0] = o4;
}

// -------------------------------- launch --------------------------------
extern "C" void kernel_launch(void* const* d_in, const int* in_sizes, int n_in,
                              void* d_out, int out_size, void* d_ws, size_t ws_size,
                              hipStream_t stream) {
  const float* inputs = (const float*)d_in[0];
  const float* W1 = (const float*)d_in[1];
  const float* W2 = (const float*)d_in[2];
  const float* b1 = (const float*)d_in[3];
  const float* b2 = (const float*)d_in[4];
  const float* lnw = (const float*)d_in[5];
  const float* lf1 = (const float*)d_in[6];
  const float* lf2 = (const float*)d_in[7];
  const int* preidx = (const int*)d_in[8];
  float* out = (float*)d_out;

  char* ws = (char*)d_ws;
  unsigned short* Xbf = (unsigned short*)(ws);                 // XROWS x 1024 = 135,266,304 B
  unsigned short* A2  = (unsigned short*)(ws + 135266304ULL);  // XROWS x  512 =  67,633,152 B
  unsigned short* Zo  = (unsigned short*)(ws + 202899456ULL);  // 65536 x 1024 = 134,217,728 B
  unsigned short* W1c = (unsigned short*)(ws + 337117184ULL);  //  512 x 2048 bf16
  unsigned short* W2c = (unsigned short*)(ws + 339214336ULL);  // 1024 x 1024 bf16
  unsigned short* c2b = (unsigned short*)(ws + 341311488ULL);  // 8 x 512
  // total ws use: ~341 MB

  prep_all<<<513, 256, 0, stream>>>(W1, W2, lf2, preidx, W1c, W2c, c2b);
  cvt_full<<<XROWS / 4, 256, 0, stream>>>(inputs, lf1, preidx, Xbf);
  // GEMM1: M=65536 x N=512, K=2048 (NH=16 pairs) -> 512 blocks (2 exact waves)
  gemm_pair<2048, 2, true, false><<<512, 512, 0, stream>>>(Xbf, W1c, A2, b1, 64, 0);
  fixup_full<<<8, 512, 0, stream>>>(Xbf, W1c, b1, c2b, A2);
  // GEMM2: M=65536 x N=1024, K=1024 (NH=8 pairs) -> 1024 blocks (4 exact waves)
  gemm_pair<1024, 4, false, true><<<1024, 512, 0, stream>>>(A2, W2c, Zo, nullptr, 128, 0);
  epilogue_full<<<BSEQ * LSEQ, 256, 0, stream>>>(Zo, Xbf, b2, lnw, out);
}

// Round 13
// 464.925 us; speedup vs baseline: 1.0554x; 1.0554x over previous
//
#include <hip/hip_runtime.h>
#include <hip/hip_bf16.h>

// LocalizedFiltering: two shifted 2-tap causal convs + residual + RMSNorm.
// Fused-K form: A'[u] = U[u] ‖ U[u+1] (U = Xbf for GEMM1, A2 for GEMM2):
//   A2[u+1] = Xbf'[u] @ [W1lo;W1hi] + b1        (K=2048, N=512)
//   Zo[u]   = A2'[u]  @ [W2lo;W2hi]             (K=1024, N=1024), then +b2+res+RMS.
// GEMM: round-8 verbatim (256x256, BK=64, paired K-tiles sharing one 257-row
// underlying A slice; vmcnt(4) mid-pair retires B_beta, vmcnt(0) pair-end).
// prep (weight transpose + c2b) merged into the cvt launch (hides under BW-bound cvt).

#define EDIM 1024
#define HDIM 512
#define LSEQ 8192
#define BSEQ 8
#define SEQR 8193                 // L+1
#define MTOT (BSEQ * SEQR)        // 65544 extended rows
#define XROWS 66048               // slack rows (zeroed)
#define CVTBLK (XROWS / 4)        // 16512 cvt blocks

using v8s = __attribute__((ext_vector_type(8))) short;
using v4f = __attribute__((ext_vector_type(4))) float;

__device__ __forceinline__ unsigned short f2b(float f) {
  union { float f; unsigned u; } v; v.f = f;
  unsigned r = v.u + 0x7fffu + ((v.u >> 16) & 1u);   // RNE
  return (unsigned short)(r >> 16);
}
__device__ __forceinline__ float b2f(unsigned short h) {
  union { unsigned u; float f; } v; v.u = ((unsigned)h) << 16; return v.f;
}
__device__ __forceinline__ void gl_lds16(const void* g, void* l) {
  __builtin_amdgcn_global_load_lds((const __attribute__((address_space(1))) void*)g,
                                   (__attribute__((address_space(3))) void*)l, 16, 0, 0);
}

// -------- merged cvt + prep: blocks [0,CVTBLK) cvt Xbf; [CVTBLK,+512) weight
// transpose-cat; last block gathers c2b. One launch, prep hides under cvt BW. --------
__device__ __forceinline__ void trns64(const float* __restrict__ src, int src_ld, int src_c0,
                                       unsigned short* __restrict__ dst, int dst_ld, int dst_k0,
                                       int n0, int k0, float (*t)[65], int tx, int ty) {
#pragma unroll
  for (int yy = 0; yy < 64; yy += 4)
    t[yy + ty][tx] = src[(size_t)(k0 + yy + ty) * src_ld + src_c0 + n0 + tx];
  __syncthreads();
#pragma unroll
  for (int yy = 0; yy < 64; yy += 4)
    dst[(size_t)(n0 + yy + ty) * dst_ld + dst_k0 + k0 + tx] = f2b(t[tx][yy + ty]);
}

__global__ __launch_bounds__(256) void cvt_prep(const float* __restrict__ inputs,
                                                const float* __restrict__ lf1,
                                                const float* __restrict__ lf2,
                                                const int* __restrict__ preidx,
                                                const float* __restrict__ W1,
                                                const float* __restrict__ W2,
                                                unsigned short* __restrict__ Xbf,
                                                unsigned short* __restrict__ W1c,
                                                unsigned short* __restrict__ W2c,
                                                unsigned short* __restrict__ c2b) {
  __shared__ float t[64][65];
  const int bk = blockIdx.x;
  const int tid = threadIdx.x;
  if (bk < CVTBLK) {               // ---- cvt: 4 ext rows per block ----
    const int r = bk * 4 + (tid >> 6);
    const int lane = tid & 63;
    unsigned short* dst = Xbf + (size_t)r * EDIM;
    if (r >= MTOT) {
#pragma unroll
      for (int c = lane * 4; c < EDIM; c += 256)
        *(ushort4*)&dst[c] = (ushort4){0, 0, 0, 0};
      return;
    }
    const int b = r / SEQR, rr = r % SEQR;
    const float* src = (rr == 0) ? (lf1 + (size_t)preidx[b] * EDIM)
                                 : (inputs + (size_t)(b * LSEQ + rr - 1) * EDIM);
#pragma unroll
    for (int c = lane * 4; c < EDIM; c += 256) {
      const float4 v = *(const float4*)(src + c);
      *(ushort4*)&dst[c] = (ushort4){f2b(v.x), f2b(v.y), f2b(v.z), f2b(v.w)};
    }
    return;
  }
  if (bk == CVTBLK + 512) {        // ---- c2b gather ----
    for (int c = tid; c < HDIM; c += 256)
#pragma unroll
      for (int b = 0; b < BSEQ; ++b)
        c2b[b * HDIM + c] = f2b(lf2[(size_t)preidx[b] * HDIM + c]);
    return;
  }
  // ---- weight transpose-cat ----
  const int s = bk - CVTBLK;       // 0..511
  const int tx = tid & 63, ty = tid >> 6;
  const int which = s >> 7, ss = s & 127;
  if (which == 0)       trns64(W1, 1024, 0,    W1c, 2048, 0,    (ss & 7) * 64,  (ss >> 3) * 64, t, tx, ty);
  else if (which == 1)  trns64(W1, 1024, 512,  W1c, 2048, 1024, (ss & 7) * 64,  (ss >> 3) * 64, t, tx, ty);
  else if (which == 2)  trns64(W2, 2048, 0,    W2c, 1024, 0,    (ss & 15) * 64, (ss >> 4) * 64, t, tx, ty);
  else                  trns64(W2, 2048, 1024, W2c, 1024, 512,  (ss & 15) * 64, (ss >> 4) * 64, t, tx, ty);
}

// -------- fixup: cache rows of A2 (blk 7) + tail rows 65537..65543 (blk 0..6) --------
__global__ __launch_bounds__(512) void fixup_full(const unsigned short* __restrict__ Xbf,
                                                  const unsigned short* __restrict__ W1c,
                                                  const float* __restrict__ b1,
                                                  const unsigned short* __restrict__ c2b,
                                                  unsigned short* __restrict__ A2) {
  const int blk = blockIdx.x;        // 0..7
  const int tid = threadIdx.x;       // 512
  if (blk == 7) {
#pragma unroll
    for (int b = 0; b < BSEQ; ++b)
      A2[(size_t)(b * SEQR) * HDIM + tid] = c2b[b * HDIM + tid];
    return;
  }
  const int r = 65536 + blk;                         // ext rows 65536..65542
  const unsigned short* a = Xbf + (size_t)r * EDIM;  // 2048 contiguous bf16
  const unsigned short* wrow = W1c + (size_t)tid * 2048;
  float s = 0.f;
  for (int k = 0; k < 2048; k += 8) {
    const v8s av = *(const v8s*)&a[k];
    const v8s wv = *(const v8s*)&wrow[k];
#pragma unroll
    for (int j = 0; j < 8; ++j)
      s += b2f((unsigned short)av[j]) * b2f((unsigned short)wv[j]);
  }
  A2[(size_t)(r + 1) * HDIM + tid] = f2b(s + b1[tid]);
}

// ======= paired-K 256x256 GEMM, BK=64, 8 waves (2m x 4n) — round-8 verbatim =======
// LDS: A pair-bufs [257r x 64c] @0/@16512 (elems); B step-bufs @33024 (B_A), @49408 (B_B).
#define PHASE(p, boA_, off_, ra_)                                                      \
  {                                                                                    \
    v8s af[2][2];                                                                      \
    _Pragma("unroll") for (int m2 = 0; m2 < 2; ++m2)                                   \
    _Pragma("unroll") for (int kx = 0; kx < 2; ++kx)                                   \
      af[m2][kx] = *(const v8s*)&lds[(boA_) +                                          \
          ((2 * (p) + m2) * 32 + wm * 16 + lr + (off_)) * 64 +                         \
          (((kx * 4 + lk) ^ (ra_)) << 3)];                                             \
    __builtin_amdgcn_s_setprio(1);                                                     \
    _Pragma("unroll") for (int m2 = 0; m2 < 2; ++m2)                                   \
    _Pragma("unroll") for (int nc = 0; nc < 4; ++nc)                                   \
    _Pragma("unroll") for (int kx = 0; kx < 2; ++kx)                                   \
      acc[2 * (p) + m2][nc] = __builtin_amdgcn_mfma_f32_16x16x32_bf16(                 \
          af[m2][kx], bf[nc][kx], acc[2 * (p) + m2][nc], 0, 0, 0);                     \
    __builtin_amdgcn_s_setprio(0);                                                     \
  }

#define LOAD_BFR(boB_)                                                                 \
  _Pragma("unroll") for (int nc = 0; nc < 4; ++nc)                                     \
  _Pragma("unroll") for (int kx = 0; kx < 2; ++kx)                                     \
    bf[nc][kx] = *(const v8s*)&lds[(boB_) + (nc * 64 + wn * 16 + lr) * 64 +            \
                                   (((kx * 4 + lk) ^ ra7a) << 3)];

#define STEP4(boA_, off_, ra_)                                                         \
  PHASE(0, boA_, off_, ra_) PHASE(1, boA_, off_, ra_)                                  \
  PHASE(2, boA_, off_, ra_) PHASE(3, boA_, off_, ra_)

template <int K, int NT, bool SHIFTC, bool AMAP>
__global__ __launch_bounds__(512, 2) void gemm_pair(const unsigned short* __restrict__ A,
                                                    const unsigned short* __restrict__ B,
                                                    unsigned short* __restrict__ C,
                                                    const float* __restrict__ bias,
                                                    int q, int r) {
  constexpr int NH = K / 128;          // pairs
  constexpr int LDA = K / 2;           // underlying row stride
  constexpr int N = NT * 256;
  constexpr int A0 = 0, A1 = 16512, B_A = 33024, B_B = 49408;   // elem offsets
  __shared__ __align__(16) unsigned short lds[65792];           // 131584 B

  const int h = blockIdx.x;
  const int xcd = h & 7, idx = h >> 3;
  const int tsw = (xcd < r ? xcd * (q + 1) : r * (q + 1) + (xcd - r) * q) + idx;
  const int mt = tsw / NT, nt = tsw % NT;   // n-fast: neighbors share A m-panel
  const size_t m0 = (size_t)mt * 256, n0 = (size_t)nt * 256;
  const int tid = threadIdx.x;
  const int w = tid >> 6, lane = tid & 63;
  const int wm = w >> 2, wn = w & 3;
  const int lr = lane & 15, lk = lane >> 4;
  const int ra7a = lr & 7, ra7b = (lr + 1) & 7;
  const int srow = tid >> 3, slot = tid & 7;
  const int gslot = slot ^ (srow & 7);            // pre-swizzled global 16B-slot
  const int dAB = srow * 64 + slot * 8;           // linear LDS dest = wavebase + lane*16B
  const int aBase = (int)m0 + (AMAP ? ((int)m0 >> 13) : 0);  // underlying base row

  // stage underlying A slice for pair i: rows aBase..aBase+256, cols [i*64, i*64+64)
  auto stageApair = [&](int dstE, int i) {
#pragma unroll
    for (int j = 0; j < 4; ++j) {
      const int rr = j * 64 + (tid >> 3);
      gl_lds16(A + (size_t)(aBase + rr) * LDA + i * 64 + ((tid & 7) ^ (rr & 7)) * 8,
               &lds[dstE + rr * 64 + (tid & 7) * 8]);
    }
    if (tid < 8)   // tail row 256 (wave-0 only; ledger safe: oldest-first retire + vmcnt(0))
      gl_lds16(A + (size_t)(aBase + 256) * LDA + i * 64 + tid * 8,
               &lds[dstE + 256 * 64 + tid * 8]);
  };
  // stage B K-tile t (256 n-rows x 64 cols), hh = row-half
  auto stageB = [&](int dstE, int hh, int t) {
    const unsigned short* s = B + (size_t)(n0 + hh * 128 + srow) * K + t * 64 + gslot * 8;
    unsigned short* d = &lds[dstE + hh * 8192 + dAB];
    gl_lds16(s, d);
    gl_lds16(s + (size_t)64 * K, d + 4096);
  };

  v4f acc[8][4];
#pragma unroll
  for (int i = 0; i < 8; ++i)
#pragma unroll
    for (int j = 0; j < 4; ++j) acc[i][j] = (v4f){0.f, 0.f, 0.f, 0.f};

  // prologue: A(pair 0) + B_A(tile 0); full drain
  stageApair(A0, 0);
  stageB(B_A, 0, 0); stageB(B_A, 1, 0);
  asm volatile("s_waitcnt vmcnt(0)" ::: "memory");
  __builtin_amdgcn_s_barrier();

#pragma unroll 1
  for (int i = 0; i < NH - 1; ++i) {
    const int boA = (i & 1) ? A1 : A0;
    const int soA = (i & 1) ? A0 : A1;
    v8s bf[4][2];
    // ---- step alpha (K-tile i): issue B(beta)[4] then A(pair i+1)[4+tail] ----
    stageB(B_B, 0, i + NH); stageB(B_B, 1, i + NH);
    stageApair(soA, i + 1);
    LOAD_BFR(B_A)
    STEP4(boA, 0, ra7a)
    // mid-pair: retire the 4 B(beta) (oldest); A(pair i+1) stays in flight
    asm volatile("s_waitcnt vmcnt(4)" ::: "memory");
    __builtin_amdgcn_s_barrier();
    // ---- step beta (K-tile i+NH): issue B(alpha, i+1)[4] ----
    stageB(B_A, 0, i + 1); stageB(B_A, 1, i + 1);
    LOAD_BFR(B_B)
    STEP4(boA, 1, ra7b)
    // pair end: drain everything (A pair i+1 had a full pair of flight time)
    asm volatile("s_waitcnt vmcnt(0)" ::: "memory");
    __builtin_amdgcn_s_barrier();
  }
  { // last pair (i = NH-1): only B(beta) staged; mid wait MUST be vmcnt(0)
    const int boA = ((NH - 1) & 1) ? A1 : A0;
    v8s bf[4][2];
    stageB(B_B, 0, 2 * NH - 1); stageB(B_B, 1, 2 * NH - 1);
    LOAD_BFR(B_A)
    STEP4(boA, 0, ra7a)
    asm volatile("s_waitcnt vmcnt(0)" ::: "memory");
    __builtin_amdgcn_s_barrier();
    LOAD_BFR(B_B)
    STEP4(boA, 1, ra7b)
  }

#pragma unroll
  for (int mr = 0; mr < 8; ++mr)
#pragma unroll
    for (int nc = 0; nc < 4; ++nc) {
      const size_t col = n0 + nc * 64 + wn * 16 + lr;
      float bv = 0.f;
      if constexpr (SHIFTC) bv = bias[col];
#pragma unroll
      for (int g = 0; g < 4; ++g) {
        const size_t row = m0 + mr * 32 + wm * 16 + lk * 4 + g + (SHIFTC ? 1 : 0);
        C[row * N + col] = f2b(acc[mr][nc][g] + bv);
      }
    }
}

// ---------- epilogue: + b2 + residual(bf16 Xbf) + RMSNorm, one block per token ----------
__global__ __launch_bounds__(256) void epilogue_full(
    const unsigned short* __restrict__ Zo, const unsigned short* __restrict__ Xbf,
    const float* __restrict__ b2, const float* __restrict__ lnw,
    float* __restrict__ out) {
  const int u = blockIdx.x;                       // token id 0..65535
  const size_t rx = (size_t)u + (u >> 13) + 1;    // token's ext row in Xbf
  const int tid = threadIdx.x;
  const int j0 = tid * 4;

  const ushort4 z = *(const ushort4*)&Zo[(size_t)u * EDIM + j0];
  const ushort4 xb = *(const ushort4*)&Xbf[rx * EDIM + j0];   // = bf16(inputs[token])
  const float4 bb = *(const float4*)&b2[j0];
  const float4 lw = *(const float4*)&lnw[j0];

  const float x0 = b2f(z.x) + bb.x + b2f(xb.x);
  const float x1 = b2f(z.y) + bb.y + b2f(xb.y);
  const float x2 = b2f(z.z) + bb.z + b2f(xb.z);
  const float x3 = b2f(z.w) + bb.w + b2f(xb.w);

  float ss = x0 * x0 + x1 * x1 + x2 * x2 + x3 * x3;
#pragma unroll
  for (int o = 32; o > 0; o >>= 1) ss += __shfl_xor(ss, o, 64);
  __shared__ float sp[4];
  if ((tid & 63) == 0) sp[tid >> 6] = ss;
  __syncthreads();
  const float tot = sp[0] + sp[1] + sp[2] + sp[3];
  const float scale = rsqrtf(tot * (1.0f / EDIM) + 1e-6f);

  float4 o4;
  o4.x = x0 * scale * lw.x; o4.y = x1 * scale * lw.y;
  o4.z = x2 * scale * lw.z; o4.w = x3 * scale * lw.w;
  *(float4*)&out[(size_t)u * EDIM + j0] = o4;
}

// -------------------------------- launch --------------------------------
extern "C" void kernel_launch(void* const* d_in, const int* in_sizes, int n_in,
                              void* d_out, int out_size, void* d_ws, size_t ws_size,
                              hipStream_t stream) {
  const float* inputs = (const float*)d_in[0];
  const float* W1 = (const float*)d_in[1];
  const float* W2 = (const float*)d_in[2];
  const float* b1 = (const float*)d_in[3];
  const float* b2 = (const float*)d_in[4];
  const float* lnw = (const float*)d_in[5];
  const float* lf1 = (const float*)d_in[6];
  const float* lf2 = (const float*)d_in[7];
  const int* preidx = (const int*)d_in[8];
  float* out = (float*)d_out;

  char* ws = (char*)d_ws;
  unsigned short* Xbf = (unsigned short*)(ws);                 // XROWS x 1024 = 135,266,304 B
  unsigned short* A2  = (unsigned short*)(ws + 135266304ULL);  // XROWS x  512 =  67,633,152 B
  unsigned short* Zo  = (unsigned short*)(ws + 202899456ULL);  // 65536 x 1024 = 134,217,728 B
  unsigned short* W1c = (unsigned short*)(ws + 337117184ULL);  //  512 x 2048 bf16
  unsigned short* W2c = (unsigned short*)(ws + 339214336ULL);  // 1024 x 1024 bf16
  unsigned short* c2b = (unsigned short*)(ws + 341311488ULL);  // 8 x 512
  // total ws use: ~341 MB

  // merged cvt + weight prep + c2b (one launch; prep hides under BW-bound cvt)
  cvt_prep<<<CVTBLK + 513, 256, 0, stream>>>(inputs, lf1, lf2, preidx, W1, W2,
                                             Xbf, W1c, W2c, c2b);
  // GEMM1: M=65536 x N=512, K=2048 (NH=16 pairs) -> 512 blocks (2 exact waves)
  gemm_pair<2048, 2, true, false><<<512, 512, 0, stream>>>(Xbf, W1c, A2, b1, 64, 0);
  fixup_full<<<8, 512, 0, stream>>>(Xbf, W1c, b1, c2b, A2);
  // GEMM2: M=65536 x N=1024, K=1024 (NH=8 pairs) -> 1024 blocks (4 exact waves)
  gemm_pair<1024, 4, false, true><<<1024, 512, 0, stream>>>(A2, W2c, Zo, nullptr, 128, 0);
  epilogue_full<<<BSEQ * LSEQ, 256, 0, stream>>>(Zo, Xbf, b2, lnw, out);
}

// Round 14
// 459.711 us; speedup vs baseline: 1.0673x; 1.0113x over previous
//
#include <hip/hip_runtime.h>
#include <hip/hip_bf16.h>

// LocalizedFiltering: two shifted 2-tap causal convs + residual + RMSNorm.
// Fused-K form: A'[u] = U[u] ‖ U[u+1] (U = Xbf for GEMM1, A2 for GEMM2):
//   A2[u+1] = Xbf'[u] @ [W1lo;W1hi] + b1        (K=2048, N=512)
//   Zo[u]   = A2'[u]  @ [W2lo;W2hi]             (K=1024, N=1024), then +b2+res+RMS.
// GEMM: round-8 verbatim (256x256, BK=64, paired K-tiles sharing one 257-row
// underlying A slice; vmcnt(4) mid-pair retires B_beta, vmcnt(0) pair-end).
// Pipeline trims: prep merged into cvt launch (r13); fixup launch ELIMINATED:
// tail rows ride as 7 extra blocks in GEMM1's grid (GEMM1-independent work);
// A2 cache rows substituted from c2b at GEMM2 stage time (per-lane gl_lds src).

#define EDIM 1024
#define HDIM 512
#define LSEQ 8192
#define BSEQ 8
#define SEQR 8193                 // L+1
#define MTOT (BSEQ * SEQR)        // 65544 extended rows
#define XROWS 66048               // slack rows (zeroed)
#define CVTBLK (XROWS / 4)        // 16512 cvt blocks

using v8s = __attribute__((ext_vector_type(8))) short;
using v4f = __attribute__((ext_vector_type(4))) float;

__device__ __forceinline__ unsigned short f2b(float f) {
  union { float f; unsigned u; } v; v.f = f;
  unsigned r = v.u + 0x7fffu + ((v.u >> 16) & 1u);   // RNE
  return (unsigned short)(r >> 16);
}
__device__ __forceinline__ float b2f(unsigned short h) {
  union { unsigned u; float f; } v; v.u = ((unsigned)h) << 16; return v.f;
}
__device__ __forceinline__ void gl_lds16(const void* g, void* l) {
  __builtin_amdgcn_global_load_lds((const __attribute__((address_space(1))) void*)g,
                                   (__attribute__((address_space(3))) void*)l, 16, 0, 0);
}

// -------- merged cvt + prep: blocks [0,CVTBLK) cvt Xbf; [CVTBLK,+512) weight
// transpose-cat; last block gathers c2b. One launch, prep hides under cvt BW. --------
__device__ __forceinline__ void trns64(const float* __restrict__ src, int src_ld, int src_c0,
                                       unsigned short* __restrict__ dst, int dst_ld, int dst_k0,
                                       int n0, int k0, float (*t)[65], int tx, int ty) {
#pragma unroll
  for (int yy = 0; yy < 64; yy += 4)
    t[yy + ty][tx] = src[(size_t)(k0 + yy + ty) * src_ld + src_c0 + n0 + tx];
  __syncthreads();
#pragma unroll
  for (int yy = 0; yy < 64; yy += 4)
    dst[(size_t)(n0 + yy + ty) * dst_ld + dst_k0 + k0 + tx] = f2b(t[tx][yy + ty]);
}

__global__ __launch_bounds__(256) void cvt_prep(const float* __restrict__ inputs,
                                                const float* __restrict__ lf1,
                                                const float* __restrict__ lf2,
                                                const int* __restrict__ preidx,
                                                const float* __restrict__ W1,
                                                const float* __restrict__ W2,
                                                unsigned short* __restrict__ Xbf,
                                                unsigned short* __restrict__ W1c,
                                                unsigned short* __restrict__ W2c,
                                                unsigned short* __restrict__ c2b) {
  __shared__ float t[64][65];
  const int bk = blockIdx.x;
  const int tid = threadIdx.x;
  if (bk < CVTBLK) {               // ---- cvt: 4 ext rows per block ----
    const int r = bk * 4 + (tid >> 6);
    const int lane = tid & 63;
    unsigned short* dst = Xbf + (size_t)r * EDIM;
    if (r >= MTOT) {
#pragma unroll
      for (int c = lane * 4; c < EDIM; c += 256)
        *(ushort4*)&dst[c] = (ushort4){0, 0, 0, 0};
      return;
    }
    const int b = r / SEQR, rr = r % SEQR;
    const float* src = (rr == 0) ? (lf1 + (size_t)preidx[b] * EDIM)
                                 : (inputs + (size_t)(b * LSEQ + rr - 1) * EDIM);
#pragma unroll
    for (int c = lane * 4; c < EDIM; c += 256) {
      const float4 v = *(const float4*)(src + c);
      *(ushort4*)&dst[c] = (ushort4){f2b(v.x), f2b(v.y), f2b(v.z), f2b(v.w)};
    }
    return;
  }
  if (bk == CVTBLK + 512) {        // ---- c2b gather ----
    for (int c = tid; c < HDIM; c += 256)
#pragma unroll
      for (int b = 0; b < BSEQ; ++b)
        c2b[b * HDIM + c] = f2b(lf2[(size_t)preidx[b] * HDIM + c]);
    return;
  }
  // ---- weight transpose-cat ----
  const int s = bk - CVTBLK;       // 0..511
  const int tx = tid & 63, ty = tid >> 6;
  const int which = s >> 7, ss = s & 127;
  if (which == 0)       trns64(W1, 1024, 0,    W1c, 2048, 0,    (ss & 7) * 64,  (ss >> 3) * 64, t, tx, ty);
  else if (which == 1)  trns64(W1, 1024, 512,  W1c, 2048, 1024, (ss & 7) * 64,  (ss >> 3) * 64, t, tx, ty);
  else if (which == 2)  trns64(W2, 2048, 0,    W2c, 1024, 0,    (ss & 15) * 64, (ss >> 4) * 64, t, tx, ty);
  else                  trns64(W2, 2048, 1024, W2c, 1024, 512,  (ss & 15) * 64, (ss >> 4) * 64, t, tx, ty);
}

// ======= paired-K 256x256 GEMM, BK=64, 8 waves (2m x 4n) — round-8 datapath =======
// LDS: A pair-bufs [257r x 64c] @0/@16512 (elems); B step-bufs @33024 (B_A), @49408 (B_B).
// TAIL: blocks h >= mainB compute A2 tail rows (GEMM1 only; independent of main work).
// CSUB: cache rows (row>>13 == row&8191, i.e. row = b*8193) substituted from c2b
//       at stage time via per-lane gl_lds source pointer (GEMM2 only).
#define PHASE(p, boA_, off_, ra_)                                                      \
  {                                                                                    \
    v8s af[2][2];                                                                      \
    _Pragma("unroll") for (int m2 = 0; m2 < 2; ++m2)                                   \
    _Pragma("unroll") for (int kx = 0; kx < 2; ++kx)                                   \
      af[m2][kx] = *(const v8s*)&lds[(boA_) +                                          \
          ((2 * (p) + m2) * 32 + wm * 16 + lr + (off_)) * 64 +                         \
          (((kx * 2 + lk) ^ (ra_)) << 3)];                                             \
    __builtin_amdgcn_s_setprio(1);                                                     \
    _Pragma("unroll") for (int m2 = 0; m2 < 2; ++m2)                                   \
    _Pragma("unroll") for (int nc = 0; nc < 4; ++nc)                                   \
    _Pragma("unroll") for (int kx = 0; kx < 2; ++kx)                                   \
      acc[2 * (p) + m2][nc] = __builtin_amdgcn_mfma_f32_16x16x32_bf16(                 \
          af[m2][kx], bf[nc][kx], acc[2 * (p) + m2][nc], 0, 0, 0);                     \
    __builtin_amdgcn_s_setprio(0);                                                     \
  }

// NOTE: kx*2+lk is wrong — keep round-8 exact: kx*4+lk. Macro below restores it.
#undef PHASE
#define PHASE(p, boA_, off_, ra_)                                                      \
  {                                                                                    \
    v8s af[2][2];                                                                      \
    _Pragma("unroll") for (int m2 = 0; m2 < 2; ++m2)                                   \
    _Pragma("unroll") for (int kx = 0; kx < 2; ++kx)                                   \
      af[m2][kx] = *(const v8s*)&lds[(boA_) +                                          \
          ((2 * (p) + m2) * 32 + wm * 16 + lr + (off_)) * 64 +                         \
          (((kx * 4 + lk) ^ (ra_)) << 3)];                                             \
    __builtin_amdgcn_s_setprio(1);                                                     \
    _Pragma("unroll") for (int m2 = 0; m2 < 2; ++m2)                                   \
    _Pragma("unroll") for (int nc = 0; nc < 4; ++nc)                                   \
    _Pragma("unroll") for (int kx = 0; kx < 2; ++kx)                                   \
      acc[2 * (p) + m2][nc] = __builtin_amdgcn_mfma_f32_16x16x32_bf16(                 \
          af[m2][kx], bf[nc][kx], acc[2 * (p) + m2][nc], 0, 0, 0);                     \
    __builtin_amdgcn_s_setprio(0);                                                     \
  }

#define LOAD_BFR(boB_)                                                                 \
  _Pragma("unroll") for (int nc = 0; nc < 4; ++nc)                                     \
  _Pragma("unroll") for (int kx = 0; kx < 2; ++kx)                                     \
    bf[nc][kx] = *(const v8s*)&lds[(boB_) + (nc * 64 + wn * 16 + lr) * 64 +            \
                                   (((kx * 4 + lk) ^ ra7a) << 3)];

#define STEP4(boA_, off_, ra_)                                                         \
  PHASE(0, boA_, off_, ra_) PHASE(1, boA_, off_, ra_)                                  \
  PHASE(2, boA_, off_, ra_) PHASE(3, boA_, off_, ra_)

template <int K, int NT, bool SHIFTC, bool AMAP, bool TAIL, bool CSUB>
__global__ __launch_bounds__(512, 2) void gemm_pair(const unsigned short* __restrict__ A,
                                                    const unsigned short* __restrict__ B,
                                                    unsigned short* __restrict__ C,
                                                    const float* __restrict__ bias,
                                                    const unsigned short* __restrict__ c2b,
                                                    int q, int r) {
  constexpr int NH = K / 128;          // pairs
  constexpr int LDA = K / 2;           // underlying row stride
  constexpr int N = NT * 256;
  constexpr int A0 = 0, A1 = 16512, B_A = 33024, B_B = 49408;   // elem offsets
  __shared__ __align__(16) unsigned short lds[65792];           // 131584 B

  const int h = blockIdx.x;
  const int mainB = 8 * q + r;         // main-grid block count

  if constexpr (TAIL) {
    if (h >= mainB) {                  // ---- tail rows 65537..65543 (GEMM1 only) ----
      const int tid = threadIdx.x;     // 512; one output col each
      const int rr = 65536 + (h - mainB);             // ext row 65536..65542
      const unsigned short* a = A + (size_t)rr * LDA; // 2048 contiguous bf16 (LDA=1024)
      const unsigned short* wrow = B + (size_t)tid * K;
      float s = 0.f;
      for (int k = 0; k < K; k += 8) {
        const v8s av = *(const v8s*)&a[k];
        const v8s wv = *(const v8s*)&wrow[k];
#pragma unroll
        for (int j = 0; j < 8; ++j)
          s += b2f((unsigned short)av[j]) * b2f((unsigned short)wv[j]);
      }
      C[(size_t)(rr + 1) * N + tid] = f2b(s + bias[tid]);
      return;
    }
  }

  const int xcd = h & 7, idx = h >> 3;
  const int tsw = (xcd < r ? xcd * (q + 1) : r * (q + 1) + (xcd - r) * q) + idx;
  const int mt = tsw / NT, nt = tsw % NT;   // n-fast: neighbors share A m-panel
  const size_t m0 = (size_t)mt * 256, n0 = (size_t)nt * 256;
  const int tid = threadIdx.x;
  const int w = tid >> 6, lane = tid & 63;
  const int wm = w >> 2, wn = w & 3;
  const int lr = lane & 15, lk = lane >> 4;
  const int ra7a = lr & 7, ra7b = (lr + 1) & 7;
  const int srow = tid >> 3, slot = tid & 7;
  const int gslot = slot ^ (srow & 7);            // pre-swizzled global 16B-slot
  const int dAB = srow * 64 + slot * 8;           // linear LDS dest = wavebase + lane*16B
  const int aBase = (int)m0 + (AMAP ? ((int)m0 >> 13) : 0);  // underlying base row

  // A source for underlying ext row `row`, pair i, 16B-slot `sl` (cache-row substitute)
  auto aSrc = [&](int row, int i, int sl) -> const unsigned short* {
    if (CSUB && ((row >> 13) == (row & 8191)))            // row == b*8193 (b<8)
      return c2b + (size_t)(row >> 13) * HDIM + i * 64 + sl * 8;
    return A + (size_t)row * LDA + i * 64 + sl * 8;
  };
  // stage underlying A slice for pair i: rows aBase..aBase+256, cols [i*64, i*64+64)
  auto stageApair = [&](int dstE, int i) {
#pragma unroll
    for (int j = 0; j < 4; ++j) {
      const int rr = j * 64 + (tid >> 3);
      gl_lds16(aSrc(aBase + rr, i, (tid & 7) ^ (rr & 7)),
               &lds[dstE + rr * 64 + (tid & 7) * 8]);
    }
    if (tid < 8)   // tail row 256 (wave-0 only; ledger safe: oldest-first retire + vmcnt(0))
      gl_lds16(aSrc(aBase + 256, i, tid),
               &lds[dstE + 256 * 64 + tid * 8]);
  };
  // stage B K-tile t (256 n-rows x 64 cols), hh = row-half
  auto stageB = [&](int dstE, int hh, int t) {
    const unsigned short* s = B + (size_t)(n0 + hh * 128 + srow) * K + t * 64 + gslot * 8;
    unsigned short* d = &lds[dstE + hh * 8192 + dAB];
    gl_lds16(s, d);
    gl_lds16(s + (size_t)64 * K, d + 4096);
  };

  v4f acc[8][4];
#pragma unroll
  for (int i = 0; i < 8; ++i)
#pragma unroll
    for (int j = 0; j < 4; ++j) acc[i][j] = (v4f){0.f, 0.f, 0.f, 0.f};

  // prologue: A(pair 0) + B_A(tile 0); full drain
  stageApair(A0, 0);
  stageB(B_A, 0, 0); stageB(B_A, 1, 0);
  asm volatile("s_waitcnt vmcnt(0)" ::: "memory");
  __builtin_amdgcn_s_barrier();

#pragma unroll 1
  for (int i = 0; i < NH - 1; ++i) {
    const int boA = (i & 1) ? A1 : A0;
    const int soA = (i & 1) ? A0 : A1;
    v8s bf[4][2];
    // ---- step alpha (K-tile i): issue B(beta)[4] then A(pair i+1)[4+tail] ----
    stageB(B_B, 0, i + NH); stageB(B_B, 1, i + NH);
    stageApair(soA, i + 1);
    LOAD_BFR(B_A)
    STEP4(boA, 0, ra7a)
    // mid-pair: retire the 4 B(beta) (oldest); A(pair i+1) stays in flight
    asm volatile("s_waitcnt vmcnt(4)" ::: "memory");
    __builtin_amdgcn_s_barrier();
    // ---- step beta (K-tile i+NH): issue B(alpha, i+1)[4] ----
    stageB(B_A, 0, i + 1); stageB(B_A, 1, i + 1);
    LOAD_BFR(B_B)
    STEP4(boA, 1, ra7b)
    // pair end: drain everything (A pair i+1 had a full pair of flight time)
    asm volatile("s_waitcnt vmcnt(0)" ::: "memory");
    __builtin_amdgcn_s_barrier();
  }
  { // last pair (i = NH-1): only B(beta) staged; mid wait MUST be vmcnt(0)
    const int boA = ((NH - 1) & 1) ? A1 : A0;
    v8s bf[4][2];
    stageB(B_B, 0, 2 * NH - 1); stageB(B_B, 1, 2 * NH - 1);
    LOAD_BFR(B_A)
    STEP4(boA, 0, ra7a)
    asm volatile("s_waitcnt vmcnt(0)" ::: "memory");
    __builtin_amdgcn_s_barrier();
    LOAD_BFR(B_B)
    STEP4(boA, 1, ra7b)
  }

#pragma unroll
  for (int mr = 0; mr < 8; ++mr)
#pragma unroll
    for (int nc = 0; nc < 4; ++nc) {
      const size_t col = n0 + nc * 64 + wn * 16 + lr;
      float bv = 0.f;
      if constexpr (SHIFTC) bv = bias[col];
#pragma unroll
      for (int g = 0; g < 4; ++g) {
        const size_t row = m0 + mr * 32 + wm * 16 + lk * 4 + g + (SHIFTC ? 1 : 0);
        C[row * N + col] = f2b(acc[mr][nc][g] + bv);
      }
    }
}

// ---------- epilogue: + b2 + residual(bf16 Xbf) + RMSNorm, one block per token ----------
__global__ __launch_bounds__(256) void epilogue_full(
    const unsigned short* __restrict__ Zo, const unsigned short* __restrict__ Xbf,
    const float* __restrict__ b2, const float* __restrict__ lnw,
    float* __restrict__ out) {
  const int u = blockIdx.x;                       // token id 0..65535
  const size_t rx = (size_t)u + (u >> 13) + 1;    // token's ext row in Xbf
  const int tid = threadIdx.x;
  const int j0 = tid * 4;

  const ushort4 z = *(const ushort4*)&Zo[(size_t)u * EDIM + j0];
  const ushort4 xb = *(const ushort4*)&Xbf[rx * EDIM + j0];   // = bf16(inputs[token])
  const float4 bb = *(const float4*)&b2[j0];
  const float4 lw = *(const float4*)&lnw[j0];

  const float x0 = b2f(z.x) + bb.x + b2f(xb.x);
  const float x1 = b2f(z.y) + bb.y + b2f(xb.y);
  const float x2 = b2f(z.z) + bb.z + b2f(xb.z);
  const float x3 = b2f(z.w) + bb.w + b2f(xb.w);

  float ss = x0 * x0 + x1 * x1 + x2 * x2 + x3 * x3;
#pragma unroll
  for (int o = 32; o > 0; o >>= 1) ss += __shfl_xor(ss, o, 64);
  __shared__ float sp[4];
  if ((tid & 63) == 0) sp[tid >> 6] = ss;
  __syncthreads();
  const float tot = sp[0] + sp[1] + sp[2] + sp[3];
  const float scale = rsqrtf(tot * (1.0f / EDIM) + 1e-6f);

  float4 o4;
  o4.x = x0 * scale * lw.x; o4.y = x1 * scale * lw.y;
  o4.z = x2 * scale * lw.z; o4.w = x3 * scale * lw.w;
  *(float4*)&out[(size_t)u * EDIM + j0] = o4;
}

// -------------------------------- launch --------------------------------
extern "C" void kernel_launch(void* const* d_in, const int* in_sizes, int n_in,
                              void* d_out, int out_size, void* d_ws, size_t ws_size,
                              hipStream_t stream) {
  const float* inputs = (const float*)d_in[0];
  const float* W1 = (const float*)d_in[1];
  const float* W2 = (const float*)d_in[2];
  const float* b1 = (const float*)d_in[3];
  const float* b2 = (const float*)d_in[4];
  const float* lnw = (const float*)d_in[5];
  const float* lf1 = (const float*)d_in[6];
  const float* lf2 = (const float*)d_in[7];
  const int* preidx = (const int*)d_in[8];
  float* out = (float*)d_out;

  char* ws = (char*)d_ws;
  unsigned short* Xbf = (unsigned short*)(ws);                 // XROWS x 1024 = 135,266,304 B
  unsigned short* A2  = (unsigned short*)(ws + 135266304ULL);  // XROWS x  512 =  67,633,152 B
  unsigned short* Zo  = (unsigned short*)(ws + 202899456ULL);  // 65536 x 1024 = 134,217,728 B
  unsigned short* W1c = (unsigned short*)(ws + 337117184ULL);  //  512 x 2048 bf16
  unsigned short* W2c = (unsigned short*)(ws + 339214336ULL);  // 1024 x 1024 bf16
  unsigned short* c2b = (unsigned short*)(ws + 341311488ULL);  // 8 x 512
  // total ws use: ~341 MB

  // merged cvt + weight prep + c2b (one launch; prep hides under BW-bound cvt)
  cvt_prep<<<CVTBLK + 513, 256, 0, stream>>>(inputs, lf1, lf2, preidx, W1, W2,
                                             Xbf, W1c, W2c, c2b);
  // GEMM1: M=65536 x N=512, K=2048 (NH=16 pairs) -> 512 main blocks + 7 tail blocks
  gemm_pair<2048, 2, true, false, true, false>
      <<<519, 512, 0, stream>>>(Xbf, W1c, A2, b1, nullptr, 64, 0);
  // GEMM2: M=65536 x N=1024, K=1024 (NH=8 pairs) -> 1024 blocks; cache rows from c2b
  gemm_pair<1024, 4, false, true, false, true>
      <<<1024, 512, 0, stream>>>(A2, W2c, Zo, nullptr, c2b, 128, 0);
  epilogue_full<<<BSEQ * LSEQ, 256, 0, stream>>>(Zo, Xbf, b2, lnw, out);
}